// Round 6
// baseline (37.395 us; speedup 1.0000x reference)
//
#include <hip/hip_runtime.h>

// Chamfer distance: x (32,2048,3) f32, y (32,2048,3) f32 -> scalar f32.
// d(q,r) = |r|^2 - 2 q.r + |q|^2, |.|^2 precomputed into float4.w.
//
// K0 (pre):  pack x,y into pts4[2][32][2048] = {x,y,z,|p|^2} in d_ws.
// K1 (main): 512 blocks x 512 threads. Block = (dir, batch, 256-query tile).
//   8 waves each scan a distinct 256-ref slice (refs via SCALAR loads:
//   wave-uniform float4 address -> s_load_dwordx16 batches) for the SAME
//   256 queries (4/lane, two f32x2 packed chains -> v_pk_fma_f32).
//   Slice-mins combined via 8KB LDS, block-summed -> partial[bid].
// K2 (final): sum 512 partials, scale by 1/(B*N).

#define BATCH 32
#define NPTS 2048
#define NPTS_TOT (BATCH * NPTS)   // 65536 per cloud

typedef float f32x2 __attribute__((ext_vector_type(2)));

__global__ __launch_bounds__(256) void chamfer_pre_kernel(
    const float* __restrict__ x, const float* __restrict__ y,
    float4* __restrict__ pts4)
{
    const int i = blockIdx.x * 256 + threadIdx.x;      // 0 .. 2*NPTS_TOT-1
    const float* src = (i < NPTS_TOT) ? x : y;
    const int p = i & (NPTS_TOT - 1);
    const float a = src[3 * p + 0];
    const float b = src[3 * p + 1];
    const float c = src[3 * p + 2];
    pts4[i] = make_float4(a, b, c, fmaf(a, a, fmaf(b, b, c * c)));
}

__global__ __launch_bounds__(512) void chamfer_min_kernel(
    const float4* __restrict__ pts4, float* __restrict__ partial)
{
    __shared__ float pm[256][8];    // 8 KB: per-query slice mins, [query][wave]
    __shared__ float sred[4];

    const int bid  = blockIdx.x;    // 512 blocks
    const int dir  = bid >> 8;
    const int b    = (bid >> 3) & 31;
    const int qt   = bid & 7;       // 8 tiles of 256 queries
    const int tid  = threadIdx.x;
    const int lane = tid & 63;
    const int wv   = __builtin_amdgcn_readfirstlane(tid >> 6);  // 0..7 uniform

    const float4* q4 = pts4 + (size_t)dir * NPTS_TOT + (size_t)b * NPTS + qt * 256;
    const float4* r4 = pts4 + (size_t)(1 - dir) * NPTS_TOT + (size_t)b * NPTS + wv * 256;

    // 4 queries per lane, packed into 2 f32x2 chains.
    f32x2 m2x[2], m2y[2], m2z[2], qn2[2], best[2];
    #pragma unroll
    for (int p = 0; p < 2; ++p) {
        const float4 Q0 = q4[lane + 64 * (2 * p + 0)];
        const float4 Q1 = q4[lane + 64 * (2 * p + 1)];
        m2x[p] = (f32x2){-2.0f * Q0.x, -2.0f * Q1.x};
        m2y[p] = (f32x2){-2.0f * Q0.y, -2.0f * Q1.y};
        m2z[p] = (f32x2){-2.0f * Q0.z, -2.0f * Q1.z};
        qn2[p] = (f32x2){Q0.w, Q1.w};
        best[p] = (f32x2){3.4e38f, 3.4e38f};
    }

    // Scan this wave's 256-ref slice; refs are wave-uniform -> scalar loads.
    #pragma unroll 8
    for (int j = 0; j < 256; ++j) {
        const float4 rp = r4[j];
        const f32x2 rx = (f32x2){rp.x, rp.x};
        const f32x2 ry = (f32x2){rp.y, rp.y};
        const f32x2 rz = (f32x2){rp.z, rp.z};
        const f32x2 rn = (f32x2){rp.w, rp.w};
        #pragma unroll
        for (int p = 0; p < 2; ++p) {
            f32x2 t = __builtin_elementwise_fma(m2x[p], rx, rn);
            t = __builtin_elementwise_fma(m2y[p], ry, t);
            t = __builtin_elementwise_fma(m2z[p], rz, t);
            best[p] = __builtin_elementwise_min(best[p], t);
        }
    }

    // Per-wave slice mins (+|q|^2, constant across slices) -> LDS.
    #pragma unroll
    for (int p = 0; p < 2; ++p) {
        const f32x2 v = best[p] + qn2[p];
        pm[lane + 64 * (2 * p + 0)][wv] = v.x;
        pm[lane + 64 * (2 * p + 1)][wv] = v.y;
    }
    __syncthreads();

    // Combine across the 8 slices (1 query per thread, first 4 waves).
    if (tid < 256) {
        const float4 v0 = *(const float4*)&pm[tid][0];
        const float4 v1 = *(const float4*)&pm[tid][4];
        float s = fminf(fminf(fminf(v0.x, v0.y), fminf(v0.z, v0.w)),
                        fminf(fminf(v1.x, v1.y), fminf(v1.z, v1.w)));
        #pragma unroll
        for (int off = 32; off > 0; off >>= 1) s += __shfl_down(s, off);
        if (lane == 0) sred[tid >> 6] = s;
    }
    __syncthreads();
    if (tid == 0) partial[bid] = sred[0] + sred[1] + sred[2] + sred[3];
}

__global__ __launch_bounds__(256) void chamfer_final_kernel(
    const float* __restrict__ partial, float* __restrict__ out)
{
    const int tid = threadIdx.x;
    float s = partial[tid] + partial[tid + 256];
    #pragma unroll
    for (int off = 32; off > 0; off >>= 1) s += __shfl_down(s, off);
    __shared__ float sred[4];
    if ((tid & 63) == 0) sred[tid >> 6] = s;
    __syncthreads();
    if (tid == 0)
        out[0] = (sred[0] + sred[1] + sred[2] + sred[3]) *
                 (1.0f / (float)(BATCH * NPTS));
}

extern "C" void kernel_launch(void* const* d_in, const int* in_sizes, int n_in,
                              void* d_out, int out_size, void* d_ws, size_t ws_size,
                              hipStream_t stream)
{
    const float* x = (const float*)d_in[0];
    const float* y = (const float*)d_in[1];
    float4* pts4   = (float4*)d_ws;                                  // 2 MB
    float* partial = (float*)((char*)d_ws + (size_t)4 * 1024 * 1024); // 512 floats
    float* out     = (float*)d_out;

    chamfer_pre_kernel<<<(2 * NPTS_TOT) / 256, 256, 0, stream>>>(x, y, pts4);
    chamfer_min_kernel<<<512, 512, 0, stream>>>(pts4, partial);
    chamfer_final_kernel<<<1, 256, 0, stream>>>(partial, out);
}

// Round 7
// 33.707 us; speedup vs baseline: 1.1094x; 1.1094x over previous
//
#include <hip/hip_runtime.h>

// Chamfer distance via MFMA: x (32,2048,3) f32, y (32,2048,3) f32 -> scalar.
// d(q,r) = |r|^2 - 2 q.r + |q|^2 packed as a K=16 bf16 dot product with
// hi/lo splits (error ~1e-4 << 2.2e-3 threshold):
//   A(query)[16] = [-2qxh,-2qxh,-2qxl,-2qxl, ... y,z ..., 1,1, qnh,qnl]
//   B(ref)  [16] = [ rxh,  rxl,  rxh,  rxl,  ... y,z ..., rnh,rnl, 1,1]
// One v_mfma_f32_32x32x16_bf16 = a full 32x32 distance tile (D = A.B).
// Both frags use the identical per-lane packing rule, so the result is
// independent of the HW's intra-K mapping; C/D layout is the m74/m101 one:
// col = lane&31 (ref), row m = (reg&3) + 8*(reg>>2) + 4*(lane>>5) (query).
//
// K0 pre:    pack QA/RB rows for both clouds (each point is query in one
//            direction, ref in the other).
// K1 main:   1024 blocks x 256 thr = (dir, batch, 32-query stripe x4 waves).
//            Each wave: 32 queries x 64 ref-tiles, 64 MFMA + running 16-reg
//            v_min; epilogue: 5-step shfl_xor butterfly -> per-query min,
//            plain stores (no atomics, fully deterministic).
// K2/K3:     two-stage sum of the 131072 per-point mins, scale 1/65536.

#define B_  32
#define N_  2048
#define PTS (B_ * N_)          // 65536 per cloud
#define ONEB 0x3F80u           // bf16 1.0

typedef short  bf16x8 __attribute__((ext_vector_type(8)));
typedef float  f32x16 __attribute__((ext_vector_type(16)));

__device__ __forceinline__ unsigned short f2b(float f) {
    unsigned u = __float_as_uint(f);
    return (unsigned short)((u + 0x7FFFu + ((u >> 16) & 1u)) >> 16);  // RTN-even
}
__device__ __forceinline__ float b2f(unsigned short h) {
    return __uint_as_float(((unsigned)h) << 16);
}
#define PK(a, b) (((unsigned)(a)) | (((unsigned)(b)) << 16))

__global__ __launch_bounds__(256) void chamfer_pre_kernel(
    const float* __restrict__ x, const float* __restrict__ y,
    unsigned* __restrict__ QA, unsigned* __restrict__ RB)
{
    const int i = blockIdx.x * 256 + threadIdx.x;   // 0 .. 2*PTS-1
    const int cloud = i >> 16;
    const int p = i & (PTS - 1);
    const float* s = cloud ? y : x;
    const float vx = s[3 * p + 0], vy = s[3 * p + 1], vz = s[3 * p + 2];

    const unsigned short xh = f2b(vx), xl = f2b(vx - b2f(xh));
    const unsigned short yh = f2b(vy), yl = f2b(vy - b2f(yh));
    const unsigned short zh = f2b(vz), zl = f2b(vz - b2f(zh));
    const float nrm = fmaf(vx, vx, fmaf(vy, vy, vz * vz));
    const unsigned short nh = f2b(nrm), nl = f2b(nrm - b2f(nh));
    const unsigned short mxh = f2b(-2.0f * b2f(xh)), mxl = f2b(-2.0f * b2f(xl));
    const unsigned short myh = f2b(-2.0f * b2f(yh)), myl = f2b(-2.0f * b2f(yl));
    const unsigned short mzh = f2b(-2.0f * b2f(zh)), mzl = f2b(-2.0f * b2f(zl));

    uint4* qa = (uint4*)QA + 2 * (size_t)i;
    uint4* rb = (uint4*)RB + 2 * (size_t)i;
    qa[0] = make_uint4(PK(mxh, mxh), PK(mxl, mxl), PK(myh, myh), PK(myl, myl));
    qa[1] = make_uint4(PK(mzh, mzh), PK(mzl, mzl), PK(ONEB, ONEB), PK(nh, nl));
    rb[0] = make_uint4(PK(xh, xl), PK(xh, xl), PK(yh, yl), PK(yh, yl));
    rb[1] = make_uint4(PK(zh, zl), PK(zh, zl), PK(nh, nl), PK(ONEB, ONEB));
}

__global__ __launch_bounds__(256) void chamfer_mfma_kernel(
    const unsigned short* __restrict__ QA, const unsigned short* __restrict__ RB,
    float* __restrict__ xym)
{
    const int bid  = blockIdx.x;          // 1024
    const int dir  = bid >> 9;
    const int b    = (bid >> 4) & 31;
    const int qs   = bid & 15;            // 16 stripes of 128 queries
    const int tid  = threadIdx.x;
    const int lane = tid & 63;
    const int w    = tid >> 6;
    const int qbase = qs * 128 + w * 32;  // this wave's 32 queries

    const unsigned short* qa = QA + ((size_t)(dir * PTS + b * N_ + qbase)) * 16;
    const unsigned short* rb = RB + ((size_t)((1 - dir) * PTS + b * N_)) * 16;
    const int loff = (lane & 31) * 16 + (lane >> 5) * 8;

    const bf16x8 afrag = *(const bf16x8*)(qa + loff);
    const f32x16 zacc = {};                    // stays zero: fresh C per tile
    f32x16 macc = zacc + 3.4e38f;              // running per-element min

    #pragma unroll 4
    for (int t = 0; t < 64; ++t) {
        const bf16x8 bfrag = *(const bf16x8*)(rb + t * 512 + loff);
        const f32x16 d =
            __builtin_amdgcn_mfma_f32_32x32x16_bf16(afrag, bfrag, zacc, 0, 0, 0);
        macc = __builtin_elementwise_min(macc, d);
    }

    // Row-min butterfly across the 32 ref-columns (lane&31) per reg.
    float rv[16];
    #pragma unroll
    for (int r = 0; r < 16; ++r) {
        float v = macc[r];
        v = fminf(v, __shfl_xor(v, 1));
        v = fminf(v, __shfl_xor(v, 2));
        v = fminf(v, __shfl_xor(v, 4));
        v = fminf(v, __shfl_xor(v, 8));
        v = fminf(v, __shfl_xor(v, 16));
        rv[r] = v;
    }
    if ((lane & 31) == 0) {
        const int h = lane >> 5;
        float* dst = xym + (size_t)dir * PTS + (size_t)b * N_ + qbase + 4 * h;
        #pragma unroll
        for (int r = 0; r < 16; ++r)
            dst[(r & 3) + 8 * (r >> 2)] = rv[r];
    }
}

__global__ __launch_bounds__(256) void chamfer_red1_kernel(
    const float4* __restrict__ mins4, float* __restrict__ part)
{
    const int tid = threadIdx.x;
    const float4 v = mins4[blockIdx.x * 256 + tid];
    float s = (v.x + v.y) + (v.z + v.w);
    #pragma unroll
    for (int off = 32; off > 0; off >>= 1) s += __shfl_down(s, off);
    __shared__ float sr[4];
    if ((tid & 63) == 0) sr[tid >> 6] = s;
    __syncthreads();
    if (tid == 0) part[blockIdx.x] = (sr[0] + sr[1]) + (sr[2] + sr[3]);
}

__global__ __launch_bounds__(128) void chamfer_red2_kernel(
    const float* __restrict__ part, float* __restrict__ out)
{
    const int tid = threadIdx.x;
    float s = part[tid];
    #pragma unroll
    for (int off = 32; off > 0; off >>= 1) s += __shfl_down(s, off);
    __shared__ float sr[2];
    if ((tid & 63) == 0) sr[tid >> 6] = s;
    __syncthreads();
    if (tid == 0) out[0] = (sr[0] + sr[1]) * (1.0f / (float)PTS);
}

extern "C" void kernel_launch(void* const* d_in, const int* in_sizes, int n_in,
                              void* d_out, int out_size, void* d_ws, size_t ws_size,
                              hipStream_t stream)
{
    const float* x = (const float*)d_in[0];
    const float* y = (const float*)d_in[1];
    char* ws = (char*)d_ws;
    unsigned* QA      = (unsigned*)(ws);                            // 4 MB
    unsigned* RB      = (unsigned*)(ws + (size_t)4  * 1024 * 1024); // 4 MB
    float*    xym     = (float*)   (ws + (size_t)8  * 1024 * 1024); // 512 KB
    float*    part    = (float*)   (ws + (size_t)8  * 1024 * 1024 + 512 * 1024);
    float*    out     = (float*)d_out;

    chamfer_pre_kernel <<<512, 256, 0, stream>>>(x, y, QA, RB);
    chamfer_mfma_kernel<<<1024, 256, 0, stream>>>((const unsigned short*)QA,
                                                  (const unsigned short*)RB, xym);
    chamfer_red1_kernel<<<128, 256, 0, stream>>>((const float4*)xym, part);
    chamfer_red2_kernel<<<1, 128, 0, stream>>>(part, out);
}

// Round 9
// 27.255 us; speedup vs baseline: 1.3720x; 1.2367x over previous
//
#include <hip/hip_runtime.h>

// Chamfer distance via MFMA, LDS-staged ref panel: x,y (32,2048,3) f32 -> scalar.
// d(q,r) = |r|^2 - 2 q.r + |q|^2 as a K=16 bf16 dot (hi/lo split, ~1e-4 err):
//   ref  row A[16] = [xh,xl,xh,xl, yh,yl,yh,yl, zh,zl,zh,zl, nh,nl, 1, 1 ]
//   query col B[16] = [-2qxh,-2qxh,-2qxl,-2qxl, ..y,z.., 1,1, qnh,qnl]
// One v_mfma_f32_32x32x16_bf16 -> 32 refs x 32 queries tile. Operands are
// packed with the identical per-lane rule (verified absmax=0 in round 7), so
// the intra-K mapping cancels. With refs as A (rows), the per-query min is
// within-lane: tree-min over 16 regs + one shfl_xor(32) -- no 80-shfl butterfly.
//
// K1: 512 blocks x 256 thr = (dir, batch, 256-query group).
//   - pack the batch's 2048 ref rows into 64 KB LDS (once per block)
//   - each of 4 waves: 2 query stripes (32 each, B-frags in registers),
//     64 tiles: 1 ds_read_b128 + 2 MFMA + 2 tree-min -> scalar macc per stripe
//   - epilogue: shfl_xor(32) min, per-lane sum, 5-step sum butterfly,
//     4-float LDS reduce -> partial[bid]. Deterministic, no atomics.
// K2: sum 512 partials, scale by 1/(B*N).

#define B_  32
#define N_  2048
#define PTS (B_ * N_)
#define ONEB 0x3F80u

typedef short  bf16x8 __attribute__((ext_vector_type(8)));
typedef float  f32x16 __attribute__((ext_vector_type(16)));

__device__ __forceinline__ unsigned short f2b(float f) {
    unsigned u = __float_as_uint(f);
    return (unsigned short)((u + 0x7FFFu + ((u >> 16) & 1u)) >> 16);  // RNE
}
__device__ __forceinline__ float b2f(unsigned short h) {
    return __uint_as_float(((unsigned)h) << 16);
}
#define PK(a, b) (((unsigned)(a)) | (((unsigned)(b)) << 16))

__global__ __launch_bounds__(256) void chamfer_mfma_kernel(
    const float* __restrict__ x, const float* __restrict__ y,
    float* __restrict__ partial)
{
    __shared__ unsigned sB[N_ * 8];   // 64 KB: 16 bf16 (8 uints) per ref point

    const int bid  = blockIdx.x;      // 512
    const int dir  = bid >> 8;
    const int b    = (bid >> 3) & 31;
    const int qg   = bid & 7;         // 8 groups of 256 queries
    const int tid  = threadIdx.x;
    const int lane = tid & 63;
    const int wv   = tid >> 6;
    const int h    = lane >> 5;       // k-half
    const int ln31 = lane & 31;

    const float* q = dir ? y : x;
    const float* r = dir ? x : y;
    const float* rb = r + (size_t)b * N_ * 3;
    const float* qb = q + ((size_t)b * N_ + qg * 256 + wv * 64) * 3;

    // ---- stage ref panel into LDS (8 points per thread) ----
    for (int p = tid; p < N_; p += 256) {
        const float vx = rb[3 * p + 0], vy = rb[3 * p + 1], vz = rb[3 * p + 2];
        const unsigned short xh = f2b(vx), xl = f2b(vx - b2f(xh));
        const unsigned short yh = f2b(vy), yl = f2b(vy - b2f(yh));
        const unsigned short zh = f2b(vz), zl = f2b(vz - b2f(zh));
        const float nrm = fmaf(vx, vx, fmaf(vy, vy, vz * vz));
        const unsigned short nh = f2b(nrm), nl = f2b(nrm - b2f(nh));
        unsigned* dst = sB + p * 8;
        dst[0] = PK(xh, xl); dst[1] = PK(xh, xl);
        dst[2] = PK(yh, yl); dst[3] = PK(yh, yl);
        dst[4] = PK(zh, zl); dst[5] = PK(zh, zl);
        dst[6] = PK(nh, nl); dst[7] = PK(ONEB, ONEB);
    }

    // ---- build 2 query B-frags in registers (stripe s: queries +s*32) ----
    bf16x8 bq[2];
    #pragma unroll
    for (int s = 0; s < 2; ++s) {
        const float* qp = qb + (size_t)(s * 32 + ln31) * 3;
        const float vx = qp[0], vy = qp[1], vz = qp[2];
        const unsigned short xh = f2b(vx), xl = f2b(vx - b2f(xh));
        const unsigned short yh = f2b(vy), yl = f2b(vy - b2f(yh));
        const unsigned short zh = f2b(vz), zl = f2b(vz - b2f(zh));
        const float nrm = fmaf(vx, vx, fmaf(vy, vy, vz * vz));
        const unsigned short nh = f2b(nrm), nl = f2b(nrm - b2f(nh));
        const unsigned short mxh = f2b(-2.0f * b2f(xh)), mxl = f2b(-2.0f * b2f(xl));
        const unsigned short myh = f2b(-2.0f * b2f(yh)), myl = f2b(-2.0f * b2f(yl));
        const unsigned short mzh = f2b(-2.0f * b2f(zh)), mzl = f2b(-2.0f * b2f(zl));
        unsigned u[4];
        if (h == 0) {
            u[0] = PK(mxh, mxh); u[1] = PK(mxl, mxl);
            u[2] = PK(myh, myh); u[3] = PK(myl, myl);
        } else {
            u[0] = PK(mzh, mzh); u[1] = PK(mzl, mzl);
            u[2] = PK(ONEB, ONEB); u[3] = PK(nh, nl);
        }
        bq[s] = *(bf16x8*)u;
    }
    __syncthreads();

    // ---- main loop: 64 ref tiles ----
    const f32x16 zacc = {};
    float macc0 = 3.4e38f, macc1 = 3.4e38f;
    const unsigned roff = ln31 * 8 + h * 4;      // uint offset within tile

    #pragma unroll 2
    for (int t = 0; t < 64; ++t) {
        const bf16x8 af = *(const bf16x8*)(sB + t * 256 + roff);
        const f32x16 d0 = __builtin_amdgcn_mfma_f32_32x32x16_bf16(af, bq[0], zacc, 0, 0, 0);
        const f32x16 d1 = __builtin_amdgcn_mfma_f32_32x32x16_bf16(af, bq[1], zacc, 0, 0, 0);
        // tree-min over the 16 ref-rows held in this lane
        float m0a = fminf(fminf(d0[0], d0[1]), fminf(d0[2], d0[3]));
        float m0b = fminf(fminf(d0[4], d0[5]), fminf(d0[6], d0[7]));
        float m0c = fminf(fminf(d0[8], d0[9]), fminf(d0[10], d0[11]));
        float m0d = fminf(fminf(d0[12], d0[13]), fminf(d0[14], d0[15]));
        macc0 = fminf(macc0, fminf(fminf(m0a, m0b), fminf(m0c, m0d)));
        float m1a = fminf(fminf(d1[0], d1[1]), fminf(d1[2], d1[3]));
        float m1b = fminf(fminf(d1[4], d1[5]), fminf(d1[6], d1[7]));
        float m1c = fminf(fminf(d1[8], d1[9]), fminf(d1[10], d1[11]));
        float m1d = fminf(fminf(d1[12], d1[13]), fminf(d1[14], d1[15]));
        macc1 = fminf(macc1, fminf(fminf(m1a, m1b), fminf(m1c, m1d)));
    }

    // ---- combine k-halves: other 16 rows live in the partner half-wave ----
    macc0 = fminf(macc0, __shfl_xor(macc0, 32));
    macc1 = fminf(macc1, __shfl_xor(macc1, 32));

    // ---- sum the 64 per-query mins of this wave ----
    float s = macc0 + macc1;                      // two distinct queries/lane
    s += __shfl_xor(s, 1);
    s += __shfl_xor(s, 2);
    s += __shfl_xor(s, 4);
    s += __shfl_xor(s, 8);
    s += __shfl_xor(s, 16);                       // lanes 0 & 32 now equal

    __syncthreads();                              // sB done; reuse as sred
    float* sred = (float*)sB;
    if (lane == 0) sred[wv] = s;
    __syncthreads();
    if (tid == 0) partial[bid] = (sred[0] + sred[1]) + (sred[2] + sred[3]);
}

__global__ __launch_bounds__(256) void chamfer_final_kernel(
    const float* __restrict__ partial, float* __restrict__ out)
{
    const int tid = threadIdx.x;
    float s = partial[tid] + partial[tid + 256];
    #pragma unroll
    for (int off = 32; off > 0; off >>= 1) s += __shfl_down(s, off);
    __shared__ float sr[4];
    if ((tid & 63) == 0) sr[tid >> 6] = s;
    __syncthreads();
    if (tid == 0)
        out[0] = ((sr[0] + sr[1]) + (sr[2] + sr[3])) * (1.0f / (float)PTS);
}

extern "C" void kernel_launch(void* const* d_in, const int* in_sizes, int n_in,
                              void* d_out, int out_size, void* d_ws, size_t ws_size,
                              hipStream_t stream)
{
    const float* x = (const float*)d_in[0];
    const float* y = (const float*)d_in[1];
    float* partial = (float*)d_ws;            // 512 floats
    float* out     = (float*)d_out;

    chamfer_mfma_kernel<<<512, 256, 0, stream>>>(x, y, partial);
    chamfer_final_kernel<<<1, 256, 0, stream>>>(partial, out);
}